// Round 2
// baseline (237.307 us; speedup 1.0000x reference)
//
#include <hip/hip_runtime.h>
#include <cstdint>
#include <climits>

// LeakyTopKActivation: out = x * mask * GAIN, mask = 1.0 on per-row top-k
// (k = 614 of 4096, stable ties by lowest index), LEAK=0.1 elsewhere.
//
// Wave-per-row design: one 64-lane wave owns a full row (64 floats/lane in
// registers). ZERO __syncthreads — all coordination is wave-synchronous
// (LDS ops are in-order within a wave; lgkmcnt fences + shfl/ballot).
// Exact selection via bracketed histogram [0.7,1.4] (the 85th percentile of
// a N(0,1) row is ~1.036 +- ~0.1 over 8192 rows) + parallel candidate
// ranking; exact bit-level binary-search fallback (wave-reduce only) if the
// bracket ever misses — correctness never depends on the distribution.

namespace {
constexpr int   N_FEAT  = 4096;
constexpr int   KSEL    = 614;      // max(int(4096*0.15),1)
constexpr int   NB      = 256;      // histogram bins in bracket
constexpr int   WPB     = 4;        // waves per block (independent rows)
constexpr int   THREADS = 64 * WPB;
constexpr int   FPL     = 16;       // float4 per lane (64 floats)
constexpr float LO_BR   = 0.70f;
constexpr float HI_BR   = 1.40f;
constexpr float GAINF   = 3.0f;
constexpr float LEAKG   = 0.3f;     // LEAK * GAIN
constexpr int   M_LIST  = 32;       // max gathered candidates in chosen bin
}

__device__ __forceinline__ void wave_fence() {
    // DS ops complete in-order within a wave; this stops compiler reordering
    // and waits LDS writes/atomics before dependent reads. No s_barrier.
    asm volatile("s_waitcnt lgkmcnt(0)" ::: "memory");
}

__device__ __forceinline__ uint32_t f2key(float f) {
    uint32_t u = __float_as_uint(f);
    return u ^ ((uint32_t)(((int32_t)u) >> 31) | 0x80000000u);
}

__global__ __launch_bounds__(THREADS)
void leaky_topk_wave(const float* __restrict__ x, float* __restrict__ out,
                     int nrows) {
    const int lane = threadIdx.x & 63;
    const int wv   = threadIdx.x >> 6;
    const int row  = blockIdx.x * WPB + wv;   // wave-uniform
    if (row >= nrows) return;

    __shared__ unsigned int hist[WPB][NB];
    __shared__ float        lv[WPB][M_LIST];
    __shared__ int          li[WPB][M_LIST];
    __shared__ unsigned int cnt[WPB];

    const float4* __restrict__ xv = (const float4*)(x + (size_t)row * N_FEAT);
    float4* __restrict__ ov       = (float4*)(out + (size_t)row * N_FEAT);

    // zero this wave's histogram (uint4 per lane) + candidate counter
    *((uint4*)&hist[wv][lane * 4]) = make_uint4(0u, 0u, 0u, 0u);
    if (lane == 0) cnt[wv] = 0u;
    wave_fence();

    // Coalesced load: 64 lanes read 64 consecutive float4s per chunk.
    float4 v[FPL];
    #pragma unroll
    for (int j = 0; j < FPL; ++j) v[j] = xv[j * 64 + lane];

    // Bracketed histogram; >=HI counted in registers (no atomics).
    const float invw = (float)NB / (HI_BR - LO_BR);
    int ca = 0;
    #pragma unroll
    for (int j = 0; j < FPL; ++j) {
        const float* e = (const float*)&v[j];
        #pragma unroll
        for (int q = 0; q < 4; ++q) {
            float f = e[q];
            if (f >= HI_BR) {
                ++ca;
            } else if (f >= LO_BR) {
                int b = (int)((f - LO_BR) * invw);
                if (b > NB - 1) b = NB - 1;      // fp-rounding safety
                atomicAdd(&hist[wv][b], 1u);
            }
        }
    }
    #pragma unroll
    for (int d = 1; d < 64; d <<= 1) ca += __shfl_xor(ca, d, 64);
    wave_fence();

    const int K2 = KSEL - ca;    // rank still needed within/below bracket

    // Per-lane 4 bins; suffix sums across the wave via shfl_down.
    uint4 bq = *((const uint4*)&hist[wv][lane * 4]);
    const int b0 = (int)bq.x, b1 = (int)bq.y, b2 = (int)bq.z, b3 = (int)bq.w;
    const int sl = b0 + b1 + b2 + b3;
    int t = sl;
    #pragma unroll
    for (int d = 1; d < 64; d <<= 1) {
        int o = __shfl_down(t, d, 64);
        if (lane + d < 64) t += o;
    }
    const int Stot = __shfl(t, 0, 64);  // total in bracket
    const int E    = t - sl;            // count in lanes above (bins > 4l+3)

    // within-lane suffix: count in bins >= (4l+q)  is  E + c_q
    const int c3 = b3, c2 = c3 + b2, c1 = c2 + b1, c0 = c1 + b0;
    int pickq = -1, gtv = 0, cinv = 0;
    if (K2 > 0) {
        if      (E + c0 >= K2 && E + c1 < K2) { pickq = 0; gtv = E + c1; cinv = b0; }
        else if (E + c1 >= K2 && E + c2 < K2) { pickq = 1; gtv = E + c2; cinv = b1; }
        else if (E + c2 >= K2 && E + c3 < K2) { pickq = 2; gtv = E + c3; cinv = b2; }
        else if (E + c3 >= K2 && E      < K2) { pickq = 3; gtv = E;      cinv = b3; }
    }
    unsigned long long pm = __ballot(pickq >= 0);
    bool fallback = (K2 <= 0) || (Stot < K2) || (pm == 0ull);
    int bsel = 0, rr = 0, cin = 0;
    if (!fallback) {
        int src = __ffsll(pm) - 1;
        bsel = src * 4 + __shfl(pickq, src, 64);
        rr   = K2 - __shfl(gtv, src, 64);     // rr-th largest inside bin, 1..cin
        cin  = __shfl(cinv, src, 64);
        if (cin > M_LIST) fallback = true;
    }

    if (!fallback) {
        // Gather (value, index) of the chosen bin (expected ~3 entries).
        #pragma unroll
        for (int j = 0; j < FPL; ++j) {
            const float* e = (const float*)&v[j];
            #pragma unroll
            for (int q = 0; q < 4; ++q) {
                float f = e[q];
                if (f >= LO_BR && f < HI_BR) {
                    int b = (int)((f - LO_BR) * invw);
                    if (b > NB - 1) b = NB - 1;
                    if (b == bsel) {
                        unsigned p = atomicAdd(&cnt[wv], 1u);
                        lv[wv][p] = f;
                        li[wv][p] = (j * 64 + lane) * 4 + q;
                    }
                }
            }
        }
        wave_fence();
        const int c = (int)cnt[wv];           // == cin <= M_LIST

        // Parallel rank (value desc, index asc — top_k's stable order).
        float fv = 0.f; int fi = 0; int rank = -1;
        if (lane < c) {
            fv = lv[wv][lane]; fi = li[wv][lane];
            rank = 0;
            for (int m2 = 0; m2 < c; ++m2) {
                float gv = lv[wv][m2]; int gi = li[wv][m2];
                rank += ((gv > fv) || (gv == fv && gi < fi)) ? 1 : 0;
            }
        }
        unsigned long long mt = __ballot(rank == rr - 1);
        int lt = __ffsll(mt) - 1;
        const float T  = __shfl(fv, lt, 64);
        const int   Ti = __shfl(fi, lt, 64);
        int cut = INT_MAX;  // accept all equals unless a tied one is excluded
        unsigned long long mn = __ballot(rank == rr);
        if (mn != 0ull) {
            int ln = __ffsll(mn) - 1;
            float fn = __shfl(fv, ln, 64);
            if (fn == T) cut = Ti + 1;
        }

        #pragma unroll
        for (int j = 0; j < FPL; ++j) {
            const float* e = (const float*)&v[j];
            float4 o; float* oe = (float*)&o;
            #pragma unroll
            for (int q = 0; q < 4; ++q) {
                float f = e[q];
                int g = (j * 64 + lane) * 4 + q;
                bool acc = (f > T) || (f == T && g < cut);
                oe[q] = f * (acc ? GAINF : LEAKG);
            }
            ov[j * 64 + lane] = o;
        }
        return;
    }

    // ---- exact fallback: bit binary search, wave-reduce only ----------------
    auto waveRedAll = [&](int c) -> int {
        #pragma unroll
        for (int d = 1; d < 64; d <<= 1) c += __shfl_xor(c, d, 64);
        return c;
    };
    auto cntGe = [&](uint32_t thr) -> int {
        int c = 0;
        #pragma unroll
        for (int j = 0; j < FPL; ++j) {
            const float* e = (const float*)&v[j];
            #pragma unroll
            for (int q = 0; q < 4; ++q)
                c += (f2key(e[q]) >= thr) ? 1 : 0;
        }
        return waveRedAll(c);
    };

    uint32_t klo = 0u, khi = 0xFFFFFFFFu;
    while (klo < khi) {                   // max key with cntGe >= KSEL
        uint32_t d   = khi - klo;
        uint32_t mid = klo + (d >> 1) + (d & 1u);
        if (cntGe(mid) >= KSEL) klo = mid; else khi = mid - 1u;
    }
    const uint32_t Tkey = klo;
    const int c_ge = cntGe(Tkey);
    const int c_gt = (Tkey == 0xFFFFFFFFu) ? 0 : cntGe(Tkey + 1u);
    const int need_eq = KSEL - c_gt;
    const int cnt_eq  = c_ge - c_gt;

    int cut = INT_MAX;
    if (need_eq < cnt_eq) {
        int l2 = 0, h2 = N_FEAT;          // smallest m: count(==Tkey, g<m) >= need_eq
        while (l2 < h2) {
            int mid = (l2 + h2) >> 1;
            int c = 0;
            #pragma unroll
            for (int j = 0; j < FPL; ++j) {
                const float* e = (const float*)&v[j];
                #pragma unroll
                for (int q = 0; q < 4; ++q) {
                    int g = (j * 64 + lane) * 4 + q;
                    c += (f2key(e[q]) == Tkey && g < mid) ? 1 : 0;
                }
            }
            if (waveRedAll(c) >= need_eq) h2 = mid; else l2 = mid + 1;
        }
        cut = l2;
    }

    #pragma unroll
    for (int j = 0; j < FPL; ++j) {
        const float* e = (const float*)&v[j];
        float4 o; float* oe = (float*)&o;
        #pragma unroll
        for (int q = 0; q < 4; ++q) {
            float f = e[q];
            uint32_t kk = f2key(f);
            int g = (j * 64 + lane) * 4 + q;
            bool acc = (kk > Tkey) || (kk == Tkey && g < cut);
            oe[q] = f * (acc ? GAINF : LEAKG);
        }
        ov[j * 64 + lane] = o;
    }
}

extern "C" void kernel_launch(void* const* d_in, const int* in_sizes, int n_in,
                              void* d_out, int out_size, void* d_ws, size_t ws_size,
                              hipStream_t stream) {
    const float* x = (const float*)d_in[0];
    float* out = (float*)d_out;
    const int nrows = in_sizes[0] / N_FEAT;
    const int blocks = (nrows + WPB - 1) / WPB;
    leaky_topk_wave<<<blocks, THREADS, 0, stream>>>(x, out, nrows);
}